// Round 3
// baseline (1988.832 us; speedup 1.0000x reference)
//
#include <hip/hip_runtime.h>

#define IN_CH 128
#define HEADS 4
#define OUT_CH 32
#define HC 128           // HEADS*OUT_CH
#define NB_SHIFT 5
#define NPB 32           // nodes per bucket

__device__ __forceinline__ unsigned flip_f32(float x) {
  unsigned u = __float_as_uint(x);
  return (u & 0x80000000u) ? ~u : (u | 0x80000000u);
}
__device__ __forceinline__ float unflip_f32(unsigned k) {
  unsigned u = (k & 0x80000000u) ? (k ^ 0x80000000u) : ~k;
  return __uint_as_float(u);
}

// proj[N][128] = x[N][128] @ W[128][128]
__global__ __launch_bounds__(256) void gemm_xW(const float* __restrict__ x,
                                               const float* __restrict__ W,
                                               float* __restrict__ proj, int N) {
  __shared__ float xs[128][132];
  __shared__ float ws[128][128];
  const int tid = threadIdx.x;
  const int row0 = blockIdx.x * 128;

  {
    const float4* Wv = (const float4*)W;
    float4* wsv = (float4*)ws;
#pragma unroll
    for (int i = 0; i < 16; ++i) wsv[i * 256 + tid] = Wv[i * 256 + tid];
  }
  {
    const int r = tid >> 1;
    const int k0 = (tid & 1) * 64;
    const int grow = row0 + r;
    const bool valid = grow < N;
    const float4* src = (const float4*)(x + (size_t)grow * IN_CH + k0);
#pragma unroll
    for (int i = 0; i < 16; ++i) {
      float4 v = valid ? src[i] : make_float4(0.f, 0.f, 0.f, 0.f);
      const int k = k0 + i * 4;
      xs[k][r] = v.x; xs[k + 1][r] = v.y; xs[k + 2][r] = v.z; xs[k + 3][r] = v.w;
    }
  }
  __syncthreads();

  const int cg = tid & 15;
  const int rg = tid >> 4;
  float acc[8][8];
#pragma unroll
  for (int r = 0; r < 8; ++r)
#pragma unroll
    for (int c = 0; c < 8; ++c) acc[r][c] = 0.f;

#pragma unroll 4
  for (int k = 0; k < 128; ++k) {
    float4 a0 = *(const float4*)&xs[k][rg * 8];
    float4 a1 = *(const float4*)&xs[k][rg * 8 + 4];
    float4 b0 = *(const float4*)&ws[k][cg * 8];
    float4 b1 = *(const float4*)&ws[k][cg * 8 + 4];
    float xv[8] = {a0.x, a0.y, a0.z, a0.w, a1.x, a1.y, a1.z, a1.w};
    float wv[8] = {b0.x, b0.y, b0.z, b0.w, b1.x, b1.y, b1.z, b1.w};
#pragma unroll
    for (int r = 0; r < 8; ++r)
#pragma unroll
      for (int c = 0; c < 8; ++c) acc[r][c] += xv[r] * wv[c];
  }

#pragma unroll
  for (int r = 0; r < 8; ++r) {
    const int grow = row0 + rg * 8 + r;
    if (grow < N) {
      float4* dst = (float4*)(proj + (size_t)grow * HC + cg * 8);
      dst[0] = make_float4(acc[r][0], acc[r][1], acc[r][2], acc[r][3]);
      dst[1] = make_float4(acc[r][4], acc[r][5], acc[r][6], acc[r][7]);
    }
  }
}

// Pass 1: per-(edge,head) scores + global per-head max.
__global__ __launch_bounds__(256) void edge_score(const float* __restrict__ proj,
                                                  const int* __restrict__ erow,
                                                  const int* __restrict__ ecol,
                                                  const float* __restrict__ att,
                                                  float* __restrict__ scores,
                                                  unsigned* __restrict__ headmax_key,
                                                  int E) {
  __shared__ unsigned blkmax[HEADS];
  const int tid = threadIdx.x;
  if (tid < HEADS) blkmax[tid] = 0u;
  __syncthreads();

  const int ch = tid & 127;
  const int h = ch >> 5;
  const int sub = tid >> 7;
  const float av = att[ch];
  float lmax = -3.0e38f;

  for (int e = blockIdx.x * 2 + sub; e < E; e += gridDim.x * 2) {
    const int row = erow[e];
    const int col = ecol[e];
    const float sv = proj[(size_t)row * HC + ch];
    const float dv = proj[(size_t)col * HC + ch];
    const float t = 1.f - 2.f / (__expf(2.f * (sv + dv)) + 1.f);  // tanh
    float p = t * av;
#pragma unroll
    for (int m = 16; m >= 1; m >>= 1) p += __shfl_xor(p, m, 64);
    if (scores && (ch & 31) == 0) scores[(size_t)e * HEADS + h] = p;
    lmax = fmaxf(lmax, p);
  }
  if ((ch & 31) == 0) atomicMax(&blkmax[h], flip_f32(lmax));
  __syncthreads();
  if (tid < HEADS) atomicMax(&headmax_key[tid], blkmax[tid]);
}

// --- destination binning: counting sort into buckets of NPB nodes ---
__global__ __launch_bounds__(256) void edge_hist(const int* __restrict__ ecol,
                                                 int* __restrict__ hist, int E) {
  const int i = blockIdx.x * 256 + threadIdx.x;
  if (i < E) atomicAdd(&hist[ecol[i] >> NB_SHIFT], 1);
}

__global__ __launch_bounds__(1024) void bucket_scan(const int* __restrict__ hist,
                                                    int* __restrict__ starts,
                                                    int* __restrict__ cursor, int nb) {
  __shared__ int s[4096];
  const int tid = threadIdx.x;
#pragma unroll
  for (int j = 0; j < 4; ++j) { const int i = tid + j * 1024; s[i] = (i < nb) ? hist[i] : 0; }
  __syncthreads();
  for (int off = 1; off < 4096; off <<= 1) {
    int v[4];
#pragma unroll
    for (int j = 0; j < 4; ++j) { const int i = tid + j * 1024; v[j] = (i >= off) ? s[i - off] : 0; }
    __syncthreads();
#pragma unroll
    for (int j = 0; j < 4; ++j) s[tid + j * 1024] += v[j];
    __syncthreads();
  }
#pragma unroll
  for (int j = 0; j < 4; ++j) {
    const int i = tid + j * 1024;
    if (i <= nb) {
      const int v = (i == 0) ? 0 : s[i - 1];
      starts[i] = v;
      cursor[i] = v;
    }
  }
}

__global__ __launch_bounds__(256) void edge_scatter_ids(const int* __restrict__ ecol,
                                                        int* __restrict__ cursor,
                                                        int* __restrict__ eid, int E) {
  const int i = blockIdx.x * 256 + threadIdx.x;
  if (i < E) {
    const int p = atomicAdd(&cursor[ecol[i] >> NB_SHIFT], 1);
    eid[p] = i;
  }
}

// Pass 2 (binned): one block per 32-node bucket; accumulate in LDS, single write-out.
__global__ __launch_bounds__(256) void edge_apply_binned(const float* __restrict__ proj,
                                                         const int* __restrict__ erow,
                                                         const int* __restrict__ ecol,
                                                         const float* __restrict__ scores,
                                                         const unsigned* __restrict__ headmax_key,
                                                         const int* __restrict__ starts,
                                                         const int* __restrict__ eid,
                                                         float* __restrict__ out, int N) {
  __shared__ __align__(16) float acc[NPB * HC];   // 16 KB
  __shared__ float nrm[NPB * HEADS];              // 512 B
  const int b = blockIdx.x;
  const int tid = threadIdx.x;
  for (int j = tid; j < NPB * HC; j += 256) acc[j] = 0.f;
  if (tid < NPB * HEADS) nrm[tid] = 0.f;
  __syncthreads();

  const int ch = tid & 127;
  const int h = ch >> 5;
  const int sub = tid >> 7;
  const float M = unflip_f32(headmax_key[h]);
  const int beg = starts[b];
  const int end = starts[b + 1];

  for (int i = beg + sub; i < end; i += 2) {
    const int e = eid[i];
    const int row = erow[e];
    const int col = ecol[e];
    const float s = scores[(size_t)e * HEADS + h];
    const float w = __expf(s - M);
    const float sv = proj[(size_t)row * HC + ch];
    atomicAdd(&acc[(col & (NPB - 1)) * HC + ch], sv * w);
    if ((ch & 31) == 0) atomicAdd(&nrm[(col & (NPB - 1)) * HEADS + h], w);
  }
  __syncthreads();

  const int node0 = b << NB_SHIFT;
#pragma unroll
  for (int j = 0; j < 4; ++j) {
    const int fi = tid + j * 256;          // float4 index within bucket, 0..1023
    const int nl = fi >> 5;
    const int c4 = fi & 31;                // float4 column
    const int node = node0 + nl;
    if (node < N) {
      const float inv = 1.f / fmaxf(nrm[nl * HEADS + (c4 >> 3)], 1e-12f);
      float4 v = *(const float4*)&acc[fi * 4];
      v.x *= inv; v.y *= inv; v.z *= inv; v.w *= inv;
      ((float4*)out)[(size_t)node * (HC / 4) + c4] = v;
    }
  }
}

// --- fallback (round-2) path, used only if ws_size is too small for binning ---
template <bool HAVE_SCORES>
__global__ __launch_bounds__(256) void edge_apply(const float* __restrict__ proj,
                                                  const int* __restrict__ erow,
                                                  const int* __restrict__ ecol,
                                                  const float* __restrict__ att,
                                                  const float* __restrict__ scores,
                                                  const unsigned* __restrict__ headmax_key,
                                                  float* __restrict__ out,
                                                  float* __restrict__ norm, int E) {
  const int tid = threadIdx.x;
  const int e = blockIdx.x * 2 + (tid >> 7);
  if (e >= E) return;
  const int ch = tid & 127;
  const int h = ch >> 5;
  const float M = unflip_f32(headmax_key[h]);
  const int row = erow[e];
  const int col = ecol[e];
  const float sv = proj[(size_t)row * HC + ch];
  float s;
  if (HAVE_SCORES) {
    s = scores[(size_t)e * HEADS + h];
  } else {
    const float dv = proj[(size_t)col * HC + ch];
    const float t = 1.f - 2.f / (__expf(2.f * (sv + dv)) + 1.f);
    float p = t * att[ch];
#pragma unroll
    for (int m = 16; m >= 1; m >>= 1) p += __shfl_xor(p, m, 64);
    s = p;
  }
  const float w = __expf(s - M);
  unsafeAtomicAdd(&out[(size_t)col * HC + ch], sv * w);
  if ((ch & 31) == 0) unsafeAtomicAdd(&norm[(size_t)col * HEADS + h], w);
}

__global__ __launch_bounds__(256) void finalize(float* __restrict__ out,
                                                const float* __restrict__ norm, int N) {
  const int idx = blockIdx.x * blockDim.x + threadIdx.x;
  const int total = N * (HC / 4);
  if (idx >= total) return;
  const int base = idx * 4;
  const int node = base >> 7;
  const int h = (base >> 5) & 3;
  const float inv = 1.f / fmaxf(norm[node * HEADS + h], 1e-12f);
  float4 v = ((float4*)out)[idx];
  v.x *= inv; v.y *= inv; v.z *= inv; v.w *= inv;
  ((float4*)out)[idx] = v;
}

extern "C" void kernel_launch(void* const* d_in, const int* in_sizes, int n_in,
                              void* d_out, int out_size, void* d_ws, size_t ws_size,
                              hipStream_t stream) {
  const float* x    = (const float*)d_in[0];
  const int*   eidx = (const int*)d_in[1];   // [2][E]
  const float* W    = (const float*)d_in[2];
  const float* att  = (const float*)d_in[3];
  float* out = (float*)d_out;

  const int N = in_sizes[0] / IN_CH;
  const int E = in_sizes[1] / 2;
  const int nb = (N + NPB - 1) >> NB_SHIFT;

  // ws layout
  float*    proj    = (float*)d_ws;                       // N*HC
  float*    norm    = proj + (size_t)N * HC;              // N*HEADS (fallback only)
  unsigned* headmax = (unsigned*)(norm + (size_t)N * HEADS);  // 4
  float*    scores  = (float*)(headmax + 4);              // E*HEADS
  int*      hist    = (int*)(scores + (size_t)E * HEADS); // nb
  int*      starts  = hist + nb;                          // nb+1
  int*      cursor  = starts + nb + 1;                    // nb+1
  int*      eid     = cursor + nb + 1;                    // E

  const size_t need_scores = (size_t)((char*)hist - (char*)d_ws);
  const size_t need_bin    = (size_t)((char*)(eid + E) - (char*)d_ws);
  const bool have_scores = ws_size >= need_scores;
  const bool have_bin    = ws_size >= need_bin;

  hipMemsetAsync(headmax, 0, 4 * sizeof(unsigned), stream);

  gemm_xW<<<(N + 127) / 128, 256, 0, stream>>>(x, W, proj, N);
  edge_score<<<2048, 256, 0, stream>>>(proj, eidx, eidx + E, att,
                                       have_scores ? scores : nullptr, headmax, E);

  if (have_bin) {
    hipMemsetAsync(hist, 0, (size_t)nb * sizeof(int), stream);
    edge_hist<<<(E + 255) / 256, 256, 0, stream>>>(eidx + E, hist, E);
    bucket_scan<<<1, 1024, 0, stream>>>(hist, starts, cursor, nb);
    edge_scatter_ids<<<(E + 255) / 256, 256, 0, stream>>>(eidx + E, cursor, eid, E);
    edge_apply_binned<<<nb, 256, 0, stream>>>(proj, eidx, eidx + E, scores, headmax,
                                              starts, eid, out, N);
  } else {
    hipMemsetAsync(out, 0, (size_t)out_size * sizeof(float), stream);
    hipMemsetAsync(norm, 0, (size_t)N * HEADS * sizeof(float), stream);
    if (have_scores)
      edge_apply<true><<<(E + 1) / 2, 256, 0, stream>>>(proj, eidx, eidx + E, att, scores,
                                                        headmax, out, norm, E);
    else
      edge_apply<false><<<(E + 1) / 2, 256, 0, stream>>>(proj, eidx, eidx + E, att, scores,
                                                         headmax, out, norm, E);
    finalize<<<(N * (HC / 4) + 255) / 256, 256, 0, stream>>>(out, norm, N);
  }
}

// Round 4
// 1820.772 us; speedup vs baseline: 1.0923x; 1.0923x over previous
//
#include <hip/hip_runtime.h>

#define IN_CH 128
#define HEADS 4
#define OUT_CH 32
#define HC 128           // HEADS*OUT_CH
#define NB_SHIFT 5
#define NPB 32           // nodes per bucket
#define BATCH 64         // edges staged per block iteration
#define SCORE_BLOCKS 6144

__device__ __forceinline__ unsigned flip_f32(float x) {
  unsigned u = __float_as_uint(x);
  return (u & 0x80000000u) ? ~u : (u | 0x80000000u);
}
__device__ __forceinline__ float unflip_f32(unsigned k) {
  unsigned u = (k & 0x80000000u) ? (k ^ 0x80000000u) : ~k;
  return __uint_as_float(u);
}
__device__ __forceinline__ float fast_tanh(float x) {
  return 1.f - 2.f / (__expf(2.f * x) + 1.f);
}

// proj[N][128] = x[N][128] @ W[128][128]
__global__ __launch_bounds__(256) void gemm_xW(const float* __restrict__ x,
                                               const float* __restrict__ W,
                                               float* __restrict__ proj, int N) {
  __shared__ float xs[128][132];
  __shared__ float ws[128][128];
  const int tid = threadIdx.x;
  const int row0 = blockIdx.x * 128;

  {
    const float4* Wv = (const float4*)W;
    float4* wsv = (float4*)ws;
#pragma unroll
    for (int i = 0; i < 16; ++i) wsv[i * 256 + tid] = Wv[i * 256 + tid];
  }
  {
    const int r = tid >> 1;
    const int k0 = (tid & 1) * 64;
    const int grow = row0 + r;
    const bool valid = grow < N;
    const float4* src = (const float4*)(x + (size_t)grow * IN_CH + k0);
#pragma unroll
    for (int i = 0; i < 16; ++i) {
      float4 v = valid ? src[i] : make_float4(0.f, 0.f, 0.f, 0.f);
      const int k = k0 + i * 4;
      xs[k][r] = v.x; xs[k + 1][r] = v.y; xs[k + 2][r] = v.z; xs[k + 3][r] = v.w;
    }
  }
  __syncthreads();

  const int cg = tid & 15;
  const int rg = tid >> 4;
  float acc[8][8];
#pragma unroll
  for (int r = 0; r < 8; ++r)
#pragma unroll
    for (int c = 0; c < 8; ++c) acc[r][c] = 0.f;

#pragma unroll 4
  for (int k = 0; k < 128; ++k) {
    float4 a0 = *(const float4*)&xs[k][rg * 8];
    float4 a1 = *(const float4*)&xs[k][rg * 8 + 4];
    float4 b0 = *(const float4*)&ws[k][cg * 8];
    float4 b1 = *(const float4*)&ws[k][cg * 8 + 4];
    float xv[8] = {a0.x, a0.y, a0.z, a0.w, a1.x, a1.y, a1.z, a1.w};
    float wv[8] = {b0.x, b0.y, b0.z, b0.w, b1.x, b1.y, b1.z, b1.w};
#pragma unroll
    for (int r = 0; r < 8; ++r)
#pragma unroll
      for (int c = 0; c < 8; ++c) acc[r][c] += xv[r] * wv[c];
  }

#pragma unroll
  for (int r = 0; r < 8; ++r) {
    const int grow = row0 + rg * 8 + r;
    if (grow < N) {
      float4* dst = (float4*)(proj + (size_t)grow * HC + cg * 8);
      dst[0] = make_float4(acc[r][0], acc[r][1], acc[r][2], acc[r][3]);
      dst[1] = make_float4(acc[r][4], acc[r][5], acc[r][6], acc[r][7]);
    }
  }
}

// Pass 1: wave-per-edge scores, 4-edge unroll (16 gathers in flight/wave).
// Lane l handles channels l and l+64. Per-block max -> plain store, reduced later.
__global__ __launch_bounds__(256) void edge_score_v2(const float* __restrict__ proj,
                                                     const int* __restrict__ erow,
                                                     const int* __restrict__ ecol,
                                                     const float* __restrict__ att,
                                                     float* __restrict__ scores,
                                                     unsigned* __restrict__ blockmax,
                                                     int E) {
  __shared__ unsigned blkmax[HEADS];
  const int tid = threadIdx.x;
  if (tid < HEADS) blkmax[tid] = 0u;
  __syncthreads();
  const int lane = tid & 63;
  const int wid = tid >> 6;
  const float a0 = att[lane];
  const float a1 = att[lane + 64];
  float lmA = -3.0e38f, lmB = -3.0e38f;
  const int stride = SCORE_BLOCKS * 4 * 4;

  for (int base = (blockIdx.x * 4 + wid) * 4; base < E; base += stride) {
    const int bu = __builtin_amdgcn_readfirstlane(base);
    if (bu + 4 <= E) {
      int r[4], c[4];
#pragma unroll
      for (int u = 0; u < 4; ++u) { r[u] = erow[bu + u]; c[u] = ecol[bu + u]; }
      float sA[4], sB[4], dA[4], dB[4];
#pragma unroll
      for (int u = 0; u < 4; ++u) {
        const float* ps = proj + (size_t)r[u] * HC;
        const float* pd = proj + (size_t)c[u] * HC;
        sA[u] = ps[lane]; sB[u] = ps[lane + 64];
        dA[u] = pd[lane]; dB[u] = pd[lane + 64];
      }
#pragma unroll
      for (int u = 0; u < 4; ++u) {
        float pA = fast_tanh(sA[u] + dA[u]) * a0;  // head (lane>>5): 0/1
        float pB = fast_tanh(sB[u] + dB[u]) * a1;  // head 2+(lane>>5)
#pragma unroll
        for (int m = 16; m >= 1; m >>= 1) {
          pA += __shfl_xor(pA, m, 64);
          pB += __shfl_xor(pB, m, 64);
        }
        lmA = fmaxf(lmA, pA);
        lmB = fmaxf(lmB, pB);
        if ((lane & 31) == 0 && scores) {
          const int hh = lane >> 5;
          scores[(size_t)(bu + u) * HEADS + hh] = pA;
          scores[(size_t)(bu + u) * HEADS + hh + 2] = pB;
        }
      }
    } else {
      for (int e = bu; e < E; ++e) {
        const int r0 = erow[e], c0 = ecol[e];
        const float* ps = proj + (size_t)r0 * HC;
        const float* pd = proj + (size_t)c0 * HC;
        float pA = fast_tanh(ps[lane] + pd[lane]) * a0;
        float pB = fast_tanh(ps[lane + 64] + pd[lane + 64]) * a1;
#pragma unroll
        for (int m = 16; m >= 1; m >>= 1) {
          pA += __shfl_xor(pA, m, 64);
          pB += __shfl_xor(pB, m, 64);
        }
        lmA = fmaxf(lmA, pA);
        lmB = fmaxf(lmB, pB);
        if ((lane & 31) == 0 && scores) {
          const int hh = lane >> 5;
          scores[(size_t)e * HEADS + hh] = pA;
          scores[(size_t)e * HEADS + hh + 2] = pB;
        }
      }
    }
  }
  if ((lane & 31) == 0) {
    const int hh = lane >> 5;
    atomicMax(&blkmax[hh], flip_f32(lmA));
    atomicMax(&blkmax[hh + 2], flip_f32(lmB));
  }
  __syncthreads();
  if (tid < HEADS) blockmax[blockIdx.x * HEADS + tid] = blkmax[tid];
}

__global__ __launch_bounds__(256) void reduce_headmax(const unsigned* __restrict__ blockmax,
                                                      float* __restrict__ headmax, int nblk) {
  __shared__ unsigned sm[HEADS];
  const int tid = threadIdx.x;
  if (tid < HEADS) sm[tid] = 0u;
  __syncthreads();
  const int h = tid & 3;
  unsigned k = 0u;
  for (int i = tid >> 2; i < nblk; i += 64) k = max(k, blockmax[i * HEADS + h]);
  atomicMax(&sm[h], k);
  __syncthreads();
  if (tid < HEADS) headmax[tid] = unflip_f32(sm[tid]);
}

// --- destination binning ---
__global__ __launch_bounds__(256) void edge_hist(const int* __restrict__ ecol,
                                                 int* __restrict__ hist, int E) {
  const int i = blockIdx.x * 256 + threadIdx.x;
  if (i < E) atomicAdd(&hist[ecol[i] >> NB_SHIFT], 1);
}

__global__ __launch_bounds__(1024) void bucket_scan(const int* __restrict__ hist,
                                                    int* __restrict__ starts,
                                                    int* __restrict__ cursor, int nb) {
  __shared__ int s[4096];
  const int tid = threadIdx.x;
#pragma unroll
  for (int j = 0; j < 4; ++j) { const int i = tid + j * 1024; s[i] = (i < nb) ? hist[i] : 0; }
  __syncthreads();
  for (int off = 1; off < 4096; off <<= 1) {
    int v[4];
#pragma unroll
    for (int j = 0; j < 4; ++j) { const int i = tid + j * 1024; v[j] = (i >= off) ? s[i - off] : 0; }
    __syncthreads();
#pragma unroll
    for (int j = 0; j < 4; ++j) s[tid + j * 1024] += v[j];
    __syncthreads();
  }
#pragma unroll
  for (int j = 0; j < 4; ++j) {
    const int i = tid + j * 1024;
    if (i <= nb) {
      const int v = (i == 0) ? 0 : s[i - 1];
      starts[i] = v;
      cursor[i] = v;
    }
  }
}

// Scatter sorted records: rc = row<<5|colLow, w4 = exp(s - M) per head.
__global__ __launch_bounds__(256) void edge_scatter_records(const int* __restrict__ erow,
                                                            const int* __restrict__ ecol,
                                                            const float4* __restrict__ scores4,
                                                            const float* __restrict__ headmax,
                                                            int* __restrict__ cursor,
                                                            int* __restrict__ rc,
                                                            float4* __restrict__ wv, int E) {
  const int i = blockIdx.x * 256 + threadIdx.x;
  if (i >= E) return;
  const float M0 = headmax[0], M1 = headmax[1], M2 = headmax[2], M3 = headmax[3];
  const int col = ecol[i];
  const int p = atomicAdd(&cursor[col >> NB_SHIFT], 1);
  rc[p] = (erow[i] << NB_SHIFT) | (col & (NPB - 1));
  const float4 s = scores4[i];
  wv[p] = make_float4(__expf(s.x - M0), __expf(s.y - M1), __expf(s.z - M2), __expf(s.w - M3));
}

// Pass 2: one block per 32-node bucket; LDS-staged metadata, 4-edge unroll,
// LDS accumulate (stride-1 -> 2-way bank alias, free), single write-out.
__global__ __launch_bounds__(256) void edge_apply_binned_v2(const float* __restrict__ proj,
                                                            const int* __restrict__ rc,
                                                            const float4* __restrict__ wv,
                                                            const int* __restrict__ starts,
                                                            float* __restrict__ out, int N) {
  __shared__ __align__(16) float acc[NPB * HC];  // 16 KB
  __shared__ float nrm[NPB * HEADS];             // 512 B
  __shared__ int s_rc[BATCH];
  __shared__ float4 s_w[BATCH];
  const int b = blockIdx.x;
  const int tid = threadIdx.x;
  const int lane = tid & 63;
  const int wid = tid >> 6;
  for (int j = tid; j < NPB * HC; j += 256) acc[j] = 0.f;
  if (tid < NPB * HEADS) nrm[tid] = 0.f;
  const int beg = starts[b];
  const int end = starts[b + 1];

  for (int pos = beg; pos < end; pos += BATCH) {
    const int cnt = min(BATCH, end - pos);
    __syncthreads();  // protect s_rc/s_w reuse (also covers acc init on first iter)
    if (tid < cnt) { s_rc[tid] = rc[pos + tid]; s_w[tid] = wv[pos + tid]; }
    __syncthreads();

    int j = wid;
    for (; j + 12 < cnt; j += 16) {
      int rcv[4]; float4 w4[4];
#pragma unroll
      for (int u = 0; u < 4; ++u) { rcv[u] = s_rc[j + u * 4]; w4[u] = s_w[j + u * 4]; }
      float v0[4], v1[4];
#pragma unroll
      for (int u = 0; u < 4; ++u) {
        const float* pr = proj + (size_t)(rcv[u] >> NB_SHIFT) * HC;
        v0[u] = pr[lane];
        v1[u] = pr[lane + 64];
      }
#pragma unroll
      for (int u = 0; u < 4; ++u) {
        const int cl = rcv[u] & (NPB - 1);
        const float w0 = (lane < 32) ? w4[u].x : w4[u].y;
        const float w1 = (lane < 32) ? w4[u].z : w4[u].w;
        atomicAdd(&acc[cl * HC + lane], v0[u] * w0);
        atomicAdd(&acc[cl * HC + 64 + lane], v1[u] * w1);
        if (lane < 4) {
          const float wn = (lane == 0) ? w4[u].x : (lane == 1) ? w4[u].y : (lane == 2) ? w4[u].z : w4[u].w;
          atomicAdd(&nrm[cl * HEADS + lane], wn);
        }
      }
    }
    for (; j < cnt; j += 4) {
      const int r = s_rc[j];
      const float4 w4 = s_w[j];
      const float* pr = proj + (size_t)(r >> NB_SHIFT) * HC;
      const float v0 = pr[lane];
      const float v1 = pr[lane + 64];
      const int cl = r & (NPB - 1);
      const float w0 = (lane < 32) ? w4.x : w4.y;
      const float w1 = (lane < 32) ? w4.z : w4.w;
      atomicAdd(&acc[cl * HC + lane], v0 * w0);
      atomicAdd(&acc[cl * HC + 64 + lane], v1 * w1);
      if (lane < 4) {
        const float wn = (lane == 0) ? w4.x : (lane == 1) ? w4.y : (lane == 2) ? w4.z : w4.w;
        atomicAdd(&nrm[cl * HEADS + lane], wn);
      }
    }
  }
  __syncthreads();

  const int node0 = b << NB_SHIFT;
#pragma unroll
  for (int j = 0; j < 4; ++j) {
    const int fi = tid + j * 256;  // float4 index within bucket
    const int nl = fi >> 5;
    const int c4 = fi & 31;
    const int node = node0 + nl;
    if (node < N) {
      const float inv = 1.f / fmaxf(nrm[nl * HEADS + (c4 >> 3)], 1e-12f);
      float4 v = *(const float4*)&acc[fi * 4];
      v.x *= inv; v.y *= inv; v.z *= inv; v.w *= inv;
      ((float4*)out)[(size_t)node * (HC / 4) + c4] = v;
    }
  }
  (void)wid;
}

// --- fallback (atomic scatter) if ws too small for binning ---
template <bool HAVE_SCORES>
__global__ __launch_bounds__(256) void edge_apply(const float* __restrict__ proj,
                                                  const int* __restrict__ erow,
                                                  const int* __restrict__ ecol,
                                                  const float* __restrict__ att,
                                                  const float* __restrict__ scores,
                                                  const float* __restrict__ headmax,
                                                  float* __restrict__ out,
                                                  float* __restrict__ norm, int E) {
  const int tid = threadIdx.x;
  const int e = blockIdx.x * 2 + (tid >> 7);
  if (e >= E) return;
  const int ch = tid & 127;
  const int h = ch >> 5;
  const float M = headmax[h];
  const int row = erow[e];
  const int col = ecol[e];
  const float sv = proj[(size_t)row * HC + ch];
  float s;
  if (HAVE_SCORES) {
    s = scores[(size_t)e * HEADS + h];
  } else {
    const float dv = proj[(size_t)col * HC + ch];
    float p = fast_tanh(sv + dv) * att[ch];
#pragma unroll
    for (int m = 16; m >= 1; m >>= 1) p += __shfl_xor(p, m, 64);
    s = p;
  }
  const float w = __expf(s - M);
  unsafeAtomicAdd(&out[(size_t)col * HC + ch], sv * w);
  if ((ch & 31) == 0) unsafeAtomicAdd(&norm[(size_t)col * HEADS + h], w);
}

__global__ __launch_bounds__(256) void finalize(float* __restrict__ out,
                                                const float* __restrict__ norm, int N) {
  const int idx = blockIdx.x * blockDim.x + threadIdx.x;
  const int total = N * (HC / 4);
  if (idx >= total) return;
  const int base = idx * 4;
  const int node = base >> 7;
  const int h = (base >> 5) & 3;
  const float inv = 1.f / fmaxf(norm[node * HEADS + h], 1e-12f);
  float4 v = ((float4*)out)[idx];
  v.x *= inv; v.y *= inv; v.z *= inv; v.w *= inv;
  ((float4*)out)[idx] = v;
}

extern "C" void kernel_launch(void* const* d_in, const int* in_sizes, int n_in,
                              void* d_out, int out_size, void* d_ws, size_t ws_size,
                              hipStream_t stream) {
  const float* x    = (const float*)d_in[0];
  const int*   eidx = (const int*)d_in[1];  // [2][E]
  const float* W    = (const float*)d_in[2];
  const float* att  = (const float*)d_in[3];
  float* out = (float*)d_out;

  const int N = in_sizes[0] / IN_CH;
  const int E = in_sizes[1] / 2;
  const int nb = (N + NPB - 1) >> NB_SHIFT;

  // ws layout (16B-aligned chunks)
  char* p = (char*)d_ws;
  float* proj = (float*)p;          p += (size_t)N * HC * 4;
  float* scores = (float*)p;        p += (size_t)E * HEADS * 4;
  unsigned* blockmax = (unsigned*)p; p += (size_t)SCORE_BLOCKS * HEADS * 4;
  float* headmax = (float*)p;       p += 16;
  int* hist = (int*)p;              p += (size_t)nb * 4;
  int* starts = (int*)p;            p += (size_t)(nb + 1) * 4;
  int* cursor = (int*)p;            p += (size_t)(nb + 1) * 4;
  p = (char*)(((size_t)p + 15) & ~(size_t)15);
  float4* wv = (float4*)p;          p += (size_t)E * 16;
  int* rc = (int*)p;                p += (size_t)E * 4;
  const size_t need_bin = (size_t)(p - (char*)d_ws);
  const size_t need_scores = (size_t)((char*)hist - (char*)d_ws);
  const bool have_scores = ws_size >= need_scores;
  const bool have_bin = ws_size >= need_bin;
  float* norm = (float*)wv;  // fallback-only alias (bin arrays unused there)

  gemm_xW<<<(N + 127) / 128, 256, 0, stream>>>(x, W, proj, N);
  edge_score_v2<<<SCORE_BLOCKS, 256, 0, stream>>>(proj, eidx, eidx + E, att,
                                                  have_scores ? scores : nullptr, blockmax, E);
  reduce_headmax<<<1, 256, 0, stream>>>(blockmax, headmax, SCORE_BLOCKS);

  if (have_bin) {
    hipMemsetAsync(hist, 0, (size_t)nb * sizeof(int), stream);
    edge_hist<<<(E + 255) / 256, 256, 0, stream>>>(eidx + E, hist, E);
    bucket_scan<<<1, 1024, 0, stream>>>(hist, starts, cursor, nb);
    edge_scatter_records<<<(E + 255) / 256, 256, 0, stream>>>(
        eidx, eidx + E, (const float4*)scores, headmax, cursor, rc, wv, E);
    edge_apply_binned_v2<<<nb, 256, 0, stream>>>(proj, rc, wv, starts, out, N);
  } else {
    hipMemsetAsync(out, 0, (size_t)out_size * sizeof(float), stream);
    hipMemsetAsync(norm, 0, (size_t)N * HEADS * sizeof(float), stream);
    if (have_scores)
      edge_apply<true><<<(E + 1) / 2, 256, 0, stream>>>(proj, eidx, eidx + E, att, scores,
                                                        headmax, out, norm, E);
    else
      edge_apply<false><<<(E + 1) / 2, 256, 0, stream>>>(proj, eidx, eidx + E, att, scores,
                                                         headmax, out, norm, E);
    finalize<<<(N * (HC / 4) + 255) / 256, 256, 0, stream>>>(out, norm, N);
  }
}

// Round 5
// 649.935 us; speedup vs baseline: 3.0600x; 2.8015x over previous
//
#include <hip/hip_runtime.h>

#define IN_CH 128
#define HEADS 4
#define OUT_CH 32
#define HC 128           // HEADS*OUT_CH
#define SCORE_BLOCKS 4096
#define CHUNK 2048       // scan chunk (256 thr x 8)

__device__ __forceinline__ unsigned flip_f32(float x) {
  unsigned u = __float_as_uint(x);
  return (u & 0x80000000u) ? ~u : (u | 0x80000000u);
}
__device__ __forceinline__ float unflip_f32(unsigned k) {
  unsigned u = (k & 0x80000000u) ? (k ^ 0x80000000u) : ~k;
  return __uint_as_float(u);
}
__device__ __forceinline__ float fast_tanh(float x) {
  return 1.f - 2.f / (__expf(2.f * x) + 1.f);
}

// proj[N][128] = x[N][128] @ W[128][128]
__global__ __launch_bounds__(256) void gemm_xW(const float* __restrict__ x,
                                               const float* __restrict__ W,
                                               float* __restrict__ proj, int N) {
  __shared__ float xs[128][132];
  __shared__ float ws[128][128];
  const int tid = threadIdx.x;
  const int row0 = blockIdx.x * 128;

  {
    const float4* Wv = (const float4*)W;
    float4* wsv = (float4*)ws;
#pragma unroll
    for (int i = 0; i < 16; ++i) wsv[i * 256 + tid] = Wv[i * 256 + tid];
  }
  {
    const int r = tid >> 1;
    const int k0 = (tid & 1) * 64;
    const int grow = row0 + r;
    const bool valid = grow < N;
    const float4* src = (const float4*)(x + (size_t)grow * IN_CH + k0);
#pragma unroll
    for (int i = 0; i < 16; ++i) {
      float4 v = valid ? src[i] : make_float4(0.f, 0.f, 0.f, 0.f);
      const int k = k0 + i * 4;
      xs[k][r] = v.x; xs[k + 1][r] = v.y; xs[k + 2][r] = v.z; xs[k + 3][r] = v.w;
    }
  }
  __syncthreads();

  const int cg = tid & 15;
  const int rg = tid >> 4;
  float acc[8][8];
#pragma unroll
  for (int r = 0; r < 8; ++r)
#pragma unroll
    for (int c = 0; c < 8; ++c) acc[r][c] = 0.f;

#pragma unroll 4
  for (int k = 0; k < 128; ++k) {
    float4 a0 = *(const float4*)&xs[k][rg * 8];
    float4 a1 = *(const float4*)&xs[k][rg * 8 + 4];
    float4 b0 = *(const float4*)&ws[k][cg * 8];
    float4 b1 = *(const float4*)&ws[k][cg * 8 + 4];
    float xv[8] = {a0.x, a0.y, a0.z, a0.w, a1.x, a1.y, a1.z, a1.w};
    float wv[8] = {b0.x, b0.y, b0.z, b0.w, b1.x, b1.y, b1.z, b1.w};
#pragma unroll
    for (int r = 0; r < 8; ++r)
#pragma unroll
      for (int c = 0; c < 8; ++c) acc[r][c] += xv[r] * wv[c];
  }

#pragma unroll
  for (int r = 0; r < 8; ++r) {
    const int grow = row0 + rg * 8 + r;
    if (grow < N) {
      float4* dst = (float4*)(proj + (size_t)grow * HC + cg * 8);
      dst[0] = make_float4(acc[r][0], acc[r][1], acc[r][2], acc[r][3]);
      dst[1] = make_float4(acc[r][4], acc[r][5], acc[r][6], acc[r][7]);
    }
  }
}

// histogram over exact destination node
__global__ __launch_bounds__(256) void edge_hist(const int* __restrict__ ecol,
                                                 int* __restrict__ hist, int E) {
  const int i = blockIdx.x * 256 + threadIdx.x;
  if (i < E) atomicAdd(&hist[ecol[i]], 1);
}

// --- hierarchical exclusive scan over nb counters ---
__device__ __forceinline__ int block_scan_excl(int tsum, int* ls, int tid, int* total) {
  ls[tid] = tsum;
  __syncthreads();
  for (int off = 1; off < 256; off <<= 1) {
    int v = (tid >= off) ? ls[tid - off] : 0;
    __syncthreads();
    ls[tid] += v;
    __syncthreads();
  }
  *total = ls[255];
  return ls[tid] - tsum;
}

__global__ __launch_bounds__(256) void k_scan_a(const int* __restrict__ hist,
                                                int* __restrict__ sums, int nb) {
  __shared__ int ls[256];
  const int tid = threadIdx.x;
  const int base = blockIdx.x * CHUNK + tid * 8;
  int t = 0;
#pragma unroll
  for (int j = 0; j < 8; ++j) { const int i = base + j; if (i < nb) t += hist[i]; }
  int total;
  block_scan_excl(t, ls, tid, &total);
  if (tid == 0) sums[blockIdx.x] = total;
}

__global__ __launch_bounds__(256) void k_scan_b(int* __restrict__ sums, int nc,
                                                int* __restrict__ starts,
                                                int* __restrict__ cursor, int nb) {
  __shared__ int ls[256];
  const int tid = threadIdx.x;
  const int t = (tid < nc) ? sums[tid] : 0;
  int total;
  const int excl = block_scan_excl(t, ls, tid, &total);
  if (tid < nc) sums[tid] = excl;
  if (tid == 0) { starts[nb] = total; cursor[nb] = total; }
}

__global__ __launch_bounds__(256) void k_scan_c(const int* __restrict__ hist,
                                                const int* __restrict__ sums,
                                                int* __restrict__ starts,
                                                int* __restrict__ cursor, int nb) {
  __shared__ int ls[256];
  const int tid = threadIdx.x;
  const int base = blockIdx.x * CHUNK + tid * 8;
  int t = 0;
#pragma unroll
  for (int j = 0; j < 8; ++j) { const int i = base + j; if (i < nb) t += hist[i]; }
  int total;
  const int excl = block_scan_excl(t, ls, tid, &total);
  int run = sums[blockIdx.x] + excl;
#pragma unroll
  for (int j = 0; j < 8; ++j) {
    const int i = base + j;
    if (i < nb) { starts[i] = run; cursor[i] = run; run += hist[i]; }
  }
}

// Fused: score (wave-per-edge, 4-unroll) + per-block head max + sorted record scatter.
template <bool SCATTER>
__global__ __launch_bounds__(256) void score_scatter(const float* __restrict__ proj,
                                                     const int* __restrict__ erow,
                                                     const int* __restrict__ ecol,
                                                     const float* __restrict__ att,
                                                     int* __restrict__ cursor,
                                                     int* __restrict__ rc,
                                                     float4* __restrict__ svec,
                                                     unsigned* __restrict__ blockmax, int E) {
  __shared__ unsigned blkmax[HEADS];
  const int tid = threadIdx.x;
  if (tid < HEADS) blkmax[tid] = 0u;
  __syncthreads();
  const int lane = tid & 63;
  const int wid = tid >> 6;
  const float a0 = att[lane];
  const float a1 = att[lane + 64];
  float lmA = -3.0e38f, lmB = -3.0e38f;
  const int stride = SCORE_BLOCKS * 16;

  for (int base = (blockIdx.x * 4 + wid) * 4; base < E; base += stride) {
    const int bu = __builtin_amdgcn_readfirstlane(base);
    if (bu + 4 <= E) {
      int r[4], c[4];
#pragma unroll
      for (int u = 0; u < 4; ++u) { r[u] = erow[bu + u]; c[u] = ecol[bu + u]; }
      float sA[4], sB[4], dA[4], dB[4];
#pragma unroll
      for (int u = 0; u < 4; ++u) {
        const float* ps = proj + (size_t)r[u] * HC;
        const float* pd = proj + (size_t)c[u] * HC;
        sA[u] = ps[lane]; sB[u] = ps[lane + 64];
        dA[u] = pd[lane]; dB[u] = pd[lane + 64];
      }
#pragma unroll
      for (int u = 0; u < 4; ++u) {
        float pA = fast_tanh(sA[u] + dA[u]) * a0;  // heads 0/1 (by lane>>5)
        float pB = fast_tanh(sB[u] + dB[u]) * a1;  // heads 2/3
#pragma unroll
        for (int m = 16; m >= 1; m >>= 1) {
          pA += __shfl_xor(pA, m, 64);
          pB += __shfl_xor(pB, m, 64);
        }
        lmA = fmaxf(lmA, pA);
        lmB = fmaxf(lmB, pB);
        if (SCATTER) {
          const float s1 = __shfl(pA, 32, 64);
          const float s3 = __shfl(pB, 32, 64);
          if (lane == 0) {
            const int p = atomicAdd(&cursor[c[u]], 1);
            rc[p] = r[u];
            svec[p] = make_float4(pA, s1, pB, s3);
          }
        }
      }
    } else {
      for (int e = bu; e < E; ++e) {
        const int r0 = erow[e], c0 = ecol[e];
        const float* ps = proj + (size_t)r0 * HC;
        const float* pd = proj + (size_t)c0 * HC;
        float pA = fast_tanh(ps[lane] + pd[lane]) * a0;
        float pB = fast_tanh(ps[lane + 64] + pd[lane + 64]) * a1;
#pragma unroll
        for (int m = 16; m >= 1; m >>= 1) {
          pA += __shfl_xor(pA, m, 64);
          pB += __shfl_xor(pB, m, 64);
        }
        lmA = fmaxf(lmA, pA);
        lmB = fmaxf(lmB, pB);
        if (SCATTER) {
          const float s1 = __shfl(pA, 32, 64);
          const float s3 = __shfl(pB, 32, 64);
          if (lane == 0) {
            const int p = atomicAdd(&cursor[c0], 1);
            rc[p] = r0;
            svec[p] = make_float4(pA, s1, pB, s3);
          }
        }
      }
    }
  }
  if ((lane & 31) == 0) {
    const int hh = lane >> 5;
    atomicMax(&blkmax[hh], flip_f32(lmA));
    atomicMax(&blkmax[hh + 2], flip_f32(lmB));
  }
  __syncthreads();
  if (tid < HEADS) blockmax[blockIdx.x * HEADS + tid] = blkmax[tid];
}

__global__ __launch_bounds__(256) void reduce_headmax(const unsigned* __restrict__ blockmax,
                                                      float* __restrict__ headmax, int nblk) {
  __shared__ unsigned sm[HEADS];
  const int tid = threadIdx.x;
  if (tid < HEADS) sm[tid] = 0u;
  __syncthreads();
  const int h = tid & 3;
  unsigned k = 0u;
  for (int i = tid >> 2; i < nblk; i += 64) k = max(k, blockmax[i * HEADS + h]);
  atomicMax(&sm[h], k);
  __syncthreads();
  if (tid < HEADS) headmax[tid] = unflip_f32(sm[tid]);
}

// One wave per node: register accumulation, zero atomics/LDS/barriers, fused divide.
__global__ __launch_bounds__(256) void csr_apply(const float* __restrict__ proj,
                                                 const int* __restrict__ rc,
                                                 const float4* __restrict__ svec,
                                                 const int* __restrict__ starts,
                                                 const float* __restrict__ headmax,
                                                 float* __restrict__ out, int N) {
  const int tid = threadIdx.x;
  const int lane = tid & 63;
  const int n = blockIdx.x * 4 + (tid >> 6);
  if (n >= N) return;
  const float Mh0 = headmax[lane >> 5];
  const float Mh1 = headmax[2 + (lane >> 5)];
  const int beg = starts[n];
  const int end = starts[n + 1];

  float acc0 = 0.f, acc1 = 0.f, den0 = 0.f, den1 = 0.f;
  int i = beg;
  for (; i + 4 <= end; i += 4) {
    int rows[4]; float4 s4[4];
#pragma unroll
    for (int u = 0; u < 4; ++u) { rows[u] = rc[i + u]; s4[u] = svec[i + u]; }
    float v0[4], v1[4];
#pragma unroll
    for (int u = 0; u < 4; ++u) {
      const float* pr = proj + (size_t)rows[u] * HC;
      v0[u] = pr[lane];
      v1[u] = pr[lane + 64];
    }
#pragma unroll
    for (int u = 0; u < 4; ++u) {
      const float sa = (lane < 32) ? s4[u].x : s4[u].y;
      const float sb = (lane < 32) ? s4[u].z : s4[u].w;
      const float e0 = __expf(sa - Mh0);
      const float e1 = __expf(sb - Mh1);
      acc0 += v0[u] * e0; den0 += e0;
      acc1 += v1[u] * e1; den1 += e1;
    }
  }
  for (; i < end; ++i) {
    const int row = rc[i];
    const float4 s4 = svec[i];
    const float* pr = proj + (size_t)row * HC;
    const float sa = (lane < 32) ? s4.x : s4.y;
    const float sb = (lane < 32) ? s4.z : s4.w;
    const float e0 = __expf(sa - Mh0);
    const float e1 = __expf(sb - Mh1);
    acc0 += pr[lane] * e0; den0 += e0;
    acc1 += pr[lane + 64] * e1; den1 += e1;
  }
  out[(size_t)n * HC + lane] = acc0 / fmaxf(den0, 1e-12f);
  out[(size_t)n * HC + 64 + lane] = acc1 / fmaxf(den1, 1e-12f);
}

// --- compact fallback (ws too small): recompute scores, global atomics ---
__global__ __launch_bounds__(256) void edge_apply_fb(const float* __restrict__ proj,
                                                     const int* __restrict__ erow,
                                                     const int* __restrict__ ecol,
                                                     const float* __restrict__ att,
                                                     const float* __restrict__ headmax,
                                                     float* __restrict__ out,
                                                     float* __restrict__ norm, int E) {
  const int tid = threadIdx.x;
  const int e = blockIdx.x * 2 + (tid >> 7);
  if (e >= E) return;
  const int ch = tid & 127;
  const int h = ch >> 5;
  const float M = headmax[h];
  const int row = erow[e];
  const int col = ecol[e];
  const float sv = proj[(size_t)row * HC + ch];
  const float dv = proj[(size_t)col * HC + ch];
  float p = fast_tanh(sv + dv) * att[ch];
#pragma unroll
  for (int m = 16; m >= 1; m >>= 1) p += __shfl_xor(p, m, 64);
  const float w = __expf(p - M);
  unsafeAtomicAdd(&out[(size_t)col * HC + ch], sv * w);
  if ((ch & 31) == 0) unsafeAtomicAdd(&norm[(size_t)col * HEADS + h], w);
}

__global__ __launch_bounds__(256) void finalize_fb(float* __restrict__ out,
                                                   const float* __restrict__ norm, int N) {
  const int idx = blockIdx.x * blockDim.x + threadIdx.x;
  const int total = N * (HC / 4);
  if (idx >= total) return;
  const int base = idx * 4;
  const int node = base >> 7;
  const int h = (base >> 5) & 3;
  const float inv = 1.f / fmaxf(norm[node * HEADS + h], 1e-12f);
  float4 v = ((float4*)out)[idx];
  v.x *= inv; v.y *= inv; v.z *= inv; v.w *= inv;
  ((float4*)out)[idx] = v;
}

extern "C" void kernel_launch(void* const* d_in, const int* in_sizes, int n_in,
                              void* d_out, int out_size, void* d_ws, size_t ws_size,
                              hipStream_t stream) {
  const float* x    = (const float*)d_in[0];
  const int*   eidx = (const int*)d_in[1];  // [2][E]: row(src) then col(dst)
  const float* W    = (const float*)d_in[2];
  const float* att  = (const float*)d_in[3];
  float* out = (float*)d_out;

  const int N = in_sizes[0] / IN_CH;
  const int E = in_sizes[1] / 2;
  const int nb = N;
  const int nc = (nb + CHUNK - 1) / CHUNK;  // scan chunks (<=256 supported)

  // ws layout (16B-aligned pieces; float4 array first for alignment)
  char* p = (char*)d_ws;
  float* proj = (float*)p;            p += (size_t)N * HC * 4;
  float4* svec = (float4*)p;          p += (size_t)E * 16;
  int* rc = (int*)p;                  p += (size_t)E * 4;
  unsigned* blockmax = (unsigned*)p;  p += (size_t)SCORE_BLOCKS * HEADS * 4;
  float* headmax = (float*)p;         p += 16;
  int* hist = (int*)p;                p += (size_t)nb * 4;
  int* starts = (int*)p;              p += (size_t)(nb + 1) * 4;
  int* cursor = (int*)p;              p += (size_t)(nb + 1) * 4;
  int* sums = (int*)p;                p += 1024;
  const size_t need_full = (size_t)(p - (char*)d_ws);
  const bool full = (ws_size >= need_full) && (nc <= 256);

  gemm_xW<<<(N + 127) / 128, 256, 0, stream>>>(x, W, proj, N);

  if (full) {
    hipMemsetAsync(hist, 0, (size_t)nb * sizeof(int), stream);
    edge_hist<<<(E + 255) / 256, 256, 0, stream>>>(eidx + E, hist, E);
    k_scan_a<<<nc, 256, 0, stream>>>(hist, sums, nb);
    k_scan_b<<<1, 256, 0, stream>>>(sums, nc, starts, cursor, nb);
    k_scan_c<<<nc, 256, 0, stream>>>(hist, sums, starts, cursor, nb);
    score_scatter<true><<<SCORE_BLOCKS, 256, 0, stream>>>(proj, eidx, eidx + E, att,
                                                          cursor, rc, svec, blockmax, E);
    reduce_headmax<<<1, 256, 0, stream>>>(blockmax, headmax, SCORE_BLOCKS);
    csr_apply<<<(N + 3) / 4, 256, 0, stream>>>(proj, rc, svec, starts, headmax, out, N);
  } else {
    // minimal-ws fallback: blockmax/headmax/norm packed right after proj
    unsigned* bm = (unsigned*)(proj + (size_t)N * HC);
    float* hm = (float*)(bm + SCORE_BLOCKS * HEADS);
    float* norm = hm + 4;
    hipMemsetAsync(out, 0, (size_t)out_size * sizeof(float), stream);
    hipMemsetAsync(norm, 0, (size_t)N * HEADS * sizeof(float), stream);
    score_scatter<false><<<SCORE_BLOCKS, 256, 0, stream>>>(proj, eidx, eidx + E, att,
                                                           nullptr, nullptr, nullptr, bm, E);
    reduce_headmax<<<1, 256, 0, stream>>>(bm, hm, SCORE_BLOCKS);
    edge_apply_fb<<<(E + 1) / 2, 256, 0, stream>>>(proj, eidx, eidx + E, att, hm, out, norm, E);
    finalize_fb<<<(N * (HC / 4) + 255) / 256, 256, 0, stream>>>(out, norm, N);
  }
}